// Round 10
// baseline (896.972 us; speedup 1.0000x reference)
//
#include <hip/hip_runtime.h>
#include <hip/hip_cooperative_groups.h>

namespace cg = cooperative_groups;

#define D 128
#define NHB2 1024          // cooperative build grid (4 blocks/CU x 256 CU)
#define MAXBUC 2048        // N <= 131072
#define SCAP 3072          // LDS staging cap per bucket (mean 1024; 64 sigma margin)
#define WP 136             // LDS pitch in bf16 elems (breaks 256B-stride bank aliasing)

typedef __attribute__((ext_vector_type(8))) short bf16x8;
typedef __attribute__((ext_vector_type(4))) float f32x4;

__device__ inline ushort f2b(float f) {   // fp32 -> bf16 RNE
  unsigned u = __float_as_uint(f);
  return (ushort)((u + 0x7fffu + ((u >> 16) & 1u)) >> 16);
}

// ---------------- MFMA GEMM: g(bf16) = x @ W^T + b ----------------
__global__ __launch_bounds__(256) void k_gemm3(
    const float* __restrict__ x, const float* __restrict__ W,
    const float* __restrict__ bias, ushort* __restrict__ g, int n) {
  __shared__ ushort sw[128 * WP];   // 34.8 KB; reused as epilogue staging
  const int tid = threadIdx.x;
  const int row0 = blockIdx.x * 64;

  for (int i = tid; i < 128 * 32; i += 256) {   // stage W fp32->bf16
    int o = i >> 5, kg = i & 31;
    float4 v = ((const float4*)W)[i];
    ushort4 h;
    h.x = f2b(v.x); h.y = f2b(v.y); h.z = f2b(v.z); h.w = f2b(v.w);
    *(ushort4*)(&sw[o * WP + kg * 4]) = h;
  }
  __syncthreads();

  const int wid = tid >> 6, lane = tid & 63;
  const int wr0 = wid * 16;
  const int col = lane & 15, quad = lane >> 4;
  int arow = row0 + wr0 + col;
  if (arow >= n) arow = n - 1;           // clamp loads; stores guarded
  const float4* xrow = (const float4*)(x + (size_t)arow * D);

  f32x4 acc[8] = {};
#pragma unroll
  for (int s = 0; s < 4; ++s) {          // K = 4 x 32
    float4 v0 = xrow[s * 8 + quad * 2];
    float4 v1 = xrow[s * 8 + quad * 2 + 1];
    bf16x8 a;
    a[0] = f2b(v0.x); a[1] = f2b(v0.y); a[2] = f2b(v0.z); a[3] = f2b(v0.w);
    a[4] = f2b(v1.x); a[5] = f2b(v1.y); a[6] = f2b(v1.z); a[7] = f2b(v1.w);
#pragma unroll
    for (int t = 0; t < 8; ++t) {
      bf16x8 bfr = *(const bf16x8*)(&sw[(t * 16 + col) * WP + s * 32 + quad * 8]);
      acc[t] = __builtin_amdgcn_mfma_f32_16x16x32_bf16(a, bfr, acc[t], 0, 0, 0);
    }
  }

  __syncthreads();   // reuse sw for output bounce
#pragma unroll
  for (int t = 0; t < 8; ++t) {
    float bcol = bias[t * 16 + col];
#pragma unroll
    for (int r = 0; r < 4; ++r) {
      int row = wr0 + quad * 4 + r;      // C layout: col=lane&15, row=quad*4+reg
      sw[row * WP + t * 16 + col] = f2b(acc[t][r] + bcol);
    }
  }
  __syncthreads();
  for (int i = tid; i < 64 * 16; i += 256) {
    int r = i >> 4, c = i & 15;
    int gr = row0 + r;
    if (gr < n)
      *(uint4*)(&g[(size_t)gr * D + c * 8]) = *(const uint4*)(&sw[r * WP + c * 8]);
  }
}

// ---------------- cooperative build (1024 blocks, 4/CU guaranteed) ----------------
// P1 hist[j][b] -> P2 region alloc (1 atomic/bucket) + per-(block,bucket) starts
// -> P3 scatter entries via LDS cursors -> P4 per-node counts: nodese + dis.
__global__ __launch_bounds__(256, 4) void k_build(
    const int* __restrict__ ei, int* __restrict__ hist, int* __restrict__ bstart,
    int* __restrict__ boff, int* __restrict__ bend, int* __restrict__ entries,
    int2* __restrict__ nodese, float* __restrict__ dis, int* __restrict__ ctr,
    int E, int N, int nbuc) {
  cg::grid_group grid = cg::this_grid();
  __shared__ int h[MAXBUC];
  __shared__ int wtot[4];
  __shared__ int woff[4];
  const int tid = threadIdx.x;
  const int j = blockIdx.x;
  const int nb = gridDim.x;              // == NHB2
  const int per = (E + nb - 1) / nb;
  const int e0 = j * per, e1 = min(E, e0 + per);
  const int wid = tid >> 6, lane = tid & 63;

  // ---- P1: per-block bucket histogram (row j of hist) ----
  if (j == 0 && tid == 0) *ctr = 0;
  for (int i = tid; i < nbuc; i += 256) h[i] = 0;
  __syncthreads();
  for (int e = e0 + tid; e < e1; e += 256) {
    int r = ei[e], c = ei[E + e];
    atomicAdd(&h[c >> 6], 1);
    atomicAdd(&h[r >> 6], 1);
  }
  __syncthreads();
  for (int i = tid; i < nbuc; i += 256) hist[(size_t)j * nbuc + i] = h[i];
  __threadfence();
  grid.sync();

  // ---- P2: per-bucket region alloc + starts (1 atomic/bucket) ----
  for (int b = j; b < nbuc; b += nb) {
    const int jb = wid * 256;
    int v0 = hist[(size_t)(jb + lane) * nbuc + b];
    int v1 = hist[(size_t)(jb + 64 + lane) * nbuc + b];
    int v2 = hist[(size_t)(jb + 128 + lane) * nbuc + b];
    int v3 = hist[(size_t)(jb + 192 + lane) * nbuc + b];
    int p1 = v0, p2 = p1 + v1, p3 = p2 + v2, s4 = p3 + v3;
    int incl = s4;
#pragma unroll
    for (int o = 1; o < 64; o <<= 1) {
      int t = __shfl_up(incl, o);
      if (lane >= o) incl += t;
    }
    if (lane == 63) wtot[wid] = incl;
    __syncthreads();
    if (tid == 0) {
      int t0 = wtot[0], t1 = wtot[1], t2 = wtot[2], t3 = wtot[3];
      int tot = t0 + t1 + t2 + t3;
      int base = atomicAdd(ctr, tot);
      woff[0] = base; woff[1] = base + t0;
      woff[2] = base + t0 + t1; woff[3] = base + t0 + t1 + t2;
      boff[b] = base; bend[b] = base + tot;
    }
    __syncthreads();
    int excl = woff[wid] + incl - s4;
    bstart[(size_t)(jb + lane) * nbuc + b] = excl;
    bstart[(size_t)(jb + 64 + lane) * nbuc + b] = excl + p1;
    bstart[(size_t)(jb + 128 + lane) * nbuc + b] = excl + p2;
    bstart[(size_t)(jb + 192 + lane) * nbuc + b] = excl + p3;
    __syncthreads();
  }
  __threadfence();
  grid.sync();

  // ---- P3: scatter packed entries (src<<6 | dest&63) via LDS cursors ----
  for (int i = tid; i < nbuc; i += 256) h[i] = bstart[(size_t)j * nbuc + i];
  __syncthreads();
  for (int e = e0 + tid; e < e1; e += 256) {
    int r = ei[e], c = ei[E + e];
    int p1 = atomicAdd(&h[c >> 6], 1);
    entries[p1] = (r << 6) | (c & 63);
    int p2 = atomicAdd(&h[r >> 6], 1);
    entries[p2] = (c << 6) | (r & 63);
  }
  __threadfence();
  grid.sync();

  // ---- P4: per-node counts -> nodese (start,cnt) + dis ----
  for (int b = j; b < nbuc; b += nb) {
    const int s = boff[b], e = bend[b];
    if (tid < 64) h[tid] = 0;
    __syncthreads();
    for (int i = s + tid; i < e; i += 256) atomicAdd(&h[entries[i] & 63], 1);
    __syncthreads();
    if (tid < 64) {                      // wave 0 shfl scan
      int v = h[tid];
      int incl = v;
#pragma unroll
      for (int o = 1; o < 64; o <<= 1) {
        int t = __shfl_up(incl, o);
        if (tid >= o) incl += t;
      }
      int gn = b * 64 + tid;
      if (gn < N) {
        nodese[gn] = make_int2(s + incl - v, v);
        dis[gn] = rsqrtf((float)(v + 1));   // +1 self loop
      }
    }
    __syncthreads();
  }
}

// ---------------- fused sort+aggregate: one block per bucket ----------------
__global__ __launch_bounds__(256) void k_aggsort(
    const int* __restrict__ entries, const int* __restrict__ boff,
    const int* __restrict__ bend, const int2* __restrict__ nodese,
    const float* __restrict__ dis, const uint* __restrict__ g32,
    float* __restrict__ out, int N) {
  __shared__ int sbuf[SCAP];     // 12 KB
  __shared__ float dbuf[SCAP];   // 12 KB
  __shared__ int lse[64], lcnt[64], lcur[64];
  __shared__ float ldis[64];
  const int b = blockIdx.x;
  const int tid = threadIdx.x;
  const int s = boff[b];
  int cnt = bend[b] - s;
  if (cnt > SCAP) cnt = SCAP;    // never triggers for random input; memory safety

  if (tid < 64) {
    int gn = b * 64 + tid;
    int2 se = (gn < N) ? nodese[gn] : make_int2(s, 0);
    int ls = se.x - s;
    int c = se.y;
    if (ls > SCAP) ls = SCAP;
    if (ls + c > SCAP) c = SCAP - ls;
    lse[tid] = ls; lcnt[tid] = c; lcur[tid] = ls;
    ldis[tid] = (gn < N) ? dis[gn] : 0.f;
  }
  __syncthreads();

  for (int i = tid; i < cnt; i += 256) {
    int en = entries[s + i];
    int src = en >> 6;
    float d = dis[src];
    int p = atomicAdd(&lcur[en & 63], 1);
    if (p < SCAP) { sbuf[p] = src; dbuf[p] = d; }
  }
  __syncthreads();

  const int wid = tid >> 6, lane = tid & 63;
  for (int jj = 0; jj < 16; ++jj) {
    int n0 = wid * 16 + jj;
    int gn = b * 64 + n0;
    if (gn >= N) break;          // nodes ascend within wave
    float dv = ldis[n0];
    uint us = g32[(size_t)gn * 64 + lane];
    float ax = __uint_as_float(us << 16) * dv;
    float ay = __uint_as_float(us & 0xffff0000u) * dv;
    int base = lse[n0], c = lcnt[n0];
    for (int cb = 0; cb < c; cb += 64) {
      int rem = c - cb; if (rem > 64) rem = 64;
      int idx = cb + lane;
      int my = (idx < c) ? sbuf[base + idx] : 0;
      float dl = (idx < c) ? dbuf[base + idx] : 0.f;
      int k = 0;
      for (; k + 7 < rem; k += 8) {
        int u0 = __shfl(my, k);     int u1 = __shfl(my, k + 1);
        int u2 = __shfl(my, k + 2); int u3 = __shfl(my, k + 3);
        int u4 = __shfl(my, k + 4); int u5 = __shfl(my, k + 5);
        int u6 = __shfl(my, k + 6); int u7 = __shfl(my, k + 7);
        float d0 = __shfl(dl, k);     float d1 = __shfl(dl, k + 1);
        float d2 = __shfl(dl, k + 2); float d3 = __shfl(dl, k + 3);
        float d4 = __shfl(dl, k + 4); float d5 = __shfl(dl, k + 5);
        float d6 = __shfl(dl, k + 6); float d7 = __shfl(dl, k + 7);
        uint a0 = g32[(size_t)u0 * 64 + lane];
        uint a1 = g32[(size_t)u1 * 64 + lane];
        uint a2 = g32[(size_t)u2 * 64 + lane];
        uint a3 = g32[(size_t)u3 * 64 + lane];
        uint a4 = g32[(size_t)u4 * 64 + lane];
        uint a5 = g32[(size_t)u5 * 64 + lane];
        uint a6 = g32[(size_t)u6 * 64 + lane];
        uint a7 = g32[(size_t)u7 * 64 + lane];
        ax = fmaf(d0, __uint_as_float(a0 << 16), ax);
        ay = fmaf(d0, __uint_as_float(a0 & 0xffff0000u), ay);
        ax = fmaf(d1, __uint_as_float(a1 << 16), ax);
        ay = fmaf(d1, __uint_as_float(a1 & 0xffff0000u), ay);
        ax = fmaf(d2, __uint_as_float(a2 << 16), ax);
        ay = fmaf(d2, __uint_as_float(a2 & 0xffff0000u), ay);
        ax = fmaf(d3, __uint_as_float(a3 << 16), ax);
        ay = fmaf(d3, __uint_as_float(a3 & 0xffff0000u), ay);
        ax = fmaf(d4, __uint_as_float(a4 << 16), ax);
        ay = fmaf(d4, __uint_as_float(a4 & 0xffff0000u), ay);
        ax = fmaf(d5, __uint_as_float(a5 << 16), ax);
        ay = fmaf(d5, __uint_as_float(a5 & 0xffff0000u), ay);
        ax = fmaf(d6, __uint_as_float(a6 << 16), ax);
        ay = fmaf(d6, __uint_as_float(a6 & 0xffff0000u), ay);
        ax = fmaf(d7, __uint_as_float(a7 << 16), ax);
        ay = fmaf(d7, __uint_as_float(a7 & 0xffff0000u), ay);
      }
      for (; k < rem; ++k) {
        int u = __shfl(my, k);
        float du = __shfl(dl, k);
        uint a = g32[(size_t)u * 64 + lane];
        ax = fmaf(du, __uint_as_float(a << 16), ax);
        ay = fmaf(du, __uint_as_float(a & 0xffff0000u), ay);
      }
    }
    float2 o;
    o.x = fmaxf(ax * dv, 0.f);
    o.y = fmaxf(ay * dv, 0.f);
    ((float2*)out)[(size_t)gn * 64 + lane] = o;
  }
}

extern "C" void kernel_launch(void* const* d_in, const int* in_sizes, int n_in,
                              void* d_out, int out_size, void* d_ws, size_t ws_size,
                              hipStream_t stream) {
  const float* x  = (const float*)d_in[0];
  const int*   ei = (const int*)d_in[1];
  const float* W  = (const float*)d_in[2];
  const float* b  = (const float*)d_in[3];
  float* out = (float*)d_out;

  int N = in_sizes[0] / D;
  int E = in_sizes[1] / 2;
  int NBUC = (N + 63) / 64;                  // 1563 for N=100k (<= MAXBUC)

  char* ws = (char*)d_ws;
  size_t off = 0;
  ushort* g    = (ushort*)(ws + off); off += (size_t)N * D * 2;        // 25.6 MB
  off = (off + 255) & ~(size_t)255;
  float* dis   = (float*)(ws + off);  off += (size_t)N * 4;
  off = (off + 255) & ~(size_t)255;
  int2* nodese = (int2*)(ws + off);   off += (size_t)N * 8;
  off = (off + 255) & ~(size_t)255;
  int* boff    = (int*)(ws + off);    off += (size_t)NBUC * 4;
  int* bend    = (int*)(ws + off);    off += (size_t)NBUC * 4;
  int* ctr     = (int*)(ws + off);    off += 256;
  off = (off + 255) & ~(size_t)255;
  int* entries = (int*)(ws + off);    off += (size_t)2 * E * 4;        // 6.4 MB
  // hist (8 MB) + bstart (6.4 MB) overlay g (25.6 MB) — dead before k_gemm3.
  // NOTE: int-element arithmetic — bstart starts at byte offset NHB2*MAXBUC*4 = 8 MB.
  int* hist    = (int*)g;
  int* bstart  = hist + (size_t)NHB2 * MAXBUC;   // 8 MB (in bytes) into g region

  // 1) graph build (one cooperative kernel; scratch lives inside g)
  void* args[] = {(void*)&ei, (void*)&hist, (void*)&bstart, (void*)&boff,
                  (void*)&bend, (void*)&entries, (void*)&nodese, (void*)&dis,
                  (void*)&ctr, (void*)&E, (void*)&N, (void*)&NBUC};
  hipLaunchCooperativeKernel((void*)k_build, dim3(NHB2), dim3(256), args, 0, stream);

  // 2) GEMM (overwrites hist/bstart region with g)
  k_gemm3<<<NBUC, 256, 0, stream>>>(x, W, b, g, N);

  // 3) fused sort + aggregation
  k_aggsort<<<NBUC, 256, 0, stream>>>(entries, boff, bend, nodese, dis,
                                      (const uint*)g, out, N);
}